// Round 5
// baseline (258.546 us; speedup 1.0000x reference)
//
#include <hip/hip_runtime.h>
#include <cstdint>
#include <cstddef>

#define J 64
#define XD 512
#define HD 1024
#define YD 16
#define PP 8
#define NN 1024

typedef __bf16 bf16;
typedef __attribute__((ext_vector_type(8))) __bf16 bf16x8;
typedef __attribute__((ext_vector_type(4))) __bf16 bf16x4;
typedef __attribute__((ext_vector_type(4))) float f32x4;

// ---------------- workspace layout (bytes) ----------------
// W1T : J*HD*XD bf16  = 67108864   @ 0
// W2T : J*YD*HD bf16  =  2097152   @ 67108864
// XBF : NN*XD   bf16  =  1048576   @ 69206016
// B1W : J*HD    f32   =   262144   @ 70254592
// B2W : J*YD    f32   =     4096   @ 70516736
// total = 70520832

__device__ __forceinline__ void gload16(const void* g, void* l) {
  __builtin_amdgcn_global_load_lds((__attribute__((address_space(1))) void*)(g),
                                   (__attribute__((address_space(3))) void*)(l),
                                   16, 0, 0);
}

// ---- K1a: W1T[j][h][x] = bf16(mu_W1[x][h] + e_W1[j][x][h]*sig_W1[x][h])
__global__ __launch_bounds__(256) void build_w1t(
    const float* __restrict__ muW1, const float* __restrict__ sigW1,
    const float* __restrict__ eW1, bf16* __restrict__ W1T) {
  __shared__ bf16 sT[64][66];  // [h-local][x-local], pad 66 for bank spread
  int b = blockIdx.x;
  int j = b >> 7;           // 128 tiles per j (8 x-tiles x 16 h-tiles)
  int xt = (b >> 4) & 7;
  int ht = b & 15;
  int x0 = xt << 6, h0 = ht << 6;
  int tid = threadIdx.x;
  int rp = tid >> 4;          // 0..15
  int cp = (tid & 15) << 2;   // 0..60
  const float* eB = eW1 + (size_t)j * (XD * HD);
#pragma unroll
  for (int p = 0; p < 4; ++p) {
    int x = rp + (p << 4);
    size_t gi = (size_t)(x0 + x) * HD + (h0 + cp);
    f32x4 e = *(const f32x4*)(eB + gi);
    f32x4 m = *(const f32x4*)(muW1 + gi);
    f32x4 s = *(const f32x4*)(sigW1 + gi);
#pragma unroll
    for (int i = 0; i < 4; ++i) sT[cp + i][x] = (bf16)(m[i] + e[i] * s[i]);
  }
  __syncthreads();
#pragma unroll
  for (int p = 0; p < 4; ++p) {
    int h = rp + (p << 4);
    bf16x4 v;
#pragma unroll
    for (int i = 0; i < 4; ++i) v[i] = sT[h][cp + i];
    *(bf16x4*)(W1T + (size_t)(j * HD + h0 + h) * XD + (x0 + cp)) = v;
  }
}

// ---- K1b: XBF, W2T, B1W, B2W
__global__ __launch_bounds__(256) void build_small(
    const float* __restrict__ x,
    const float* __restrict__ muW2, const float* __restrict__ sigW2,
    const float* __restrict__ eW2,
    const float* __restrict__ mub1, const float* __restrict__ sigb1,
    const float* __restrict__ eb1,
    const float* __restrict__ mub2, const float* __restrict__ sigb2,
    const float* __restrict__ eb2,
    bf16* __restrict__ XBF, bf16* __restrict__ W2T,
    float* __restrict__ B1W, float* __restrict__ B2W) {
  int i = blockIdx.x * 256 + threadIdx.x;
  const int c0 = NN * XD;        // 524288
  const int c1 = J * YD * HD;    // 1048576
  const int c2 = J * HD;         // 65536
  const int c3 = J * YD;         // 1024
  if (i < c0) { XBF[i] = (bf16)x[i]; return; }
  i -= c0;
  if (i < c1) {
    int h = i & (HD - 1);
    int jy = i >> 10;
    int y = jy & 15;
    int j = jy >> 4;
    float mu = muW2[h * YD + y], sg = sigW2[h * YD + y];
    float e = eW2[((size_t)j * HD + h) * YD + y];
    W2T[i] = (bf16)(mu + e * sg);
    return;
  }
  i -= c1;
  if (i < c2) {
    int h = i & (HD - 1);
    B1W[i] = mub1[h] + eb1[i] * sigb1[h];
    return;
  }
  i -= c2;
  if (i < c3) {
    int y = i & 15;
    B2W[i] = mub2[y] + eb2[i] * sigb2[y];
  }
}

// ---- K2: fused GEMM1 + clip + GEMM2 + permutation scatter
// block = (j, 256-row n tile); 512 threads = 8 waves (2n x 4h), wave tile 128x64
// LDS 160KB: sA dbuf 2x32KB @0, sB dbuf 2x32KB @65536, sH [256][64] 32KB @131072
// counted 2-phase: stage(t+1) issued BEFORE compute(t); one vmcnt(0)+s_barrier per tile
// NOTE: no min-waves in launch_bounds — R4's (512,2) clamped VGPR=128 and spilled
// (FETCH +34MB / WRITE +26MB of scratch). ~220 regs needs the full 256 budget.
__global__ __launch_bounds__(512) void fused_mlp(
    const bf16* __restrict__ XBF, const bf16* __restrict__ W1T,
    const bf16* __restrict__ W2T, const float* __restrict__ B1W,
    const float* __restrict__ B2W, const float* __restrict__ permu,
    float* __restrict__ out) {
  extern __shared__ char smem[];          // 163840 bytes

  int bid = blockIdx.x;
  // XCD swizzle (R2-proven pattern): XCD x owns j in [8x,8x+8); the 4 n-tiles
  // of each j are adjacent on one XCD so the W1T j-chunk is L2-shared.
  int L = ((bid & 7) << 5) | (bid >> 3);
  int j = L >> 2;
  int n0 = (L & 3) << 8;

  int tid = threadIdx.x;
  int wid = tid >> 6;               // 0..7
  int lane = tid & 63;
  int l15 = lane & 15;
  int lg = lane >> 4;               // 0..3
  int wn = (wid >> 2) << 7;         // wave n offset (0 or 128)
  int wh = (wid & 3) << 6;          // wave h offset (0,64,128,192)
  int srow = tid >> 3;              // staging row 0..63 (+64 per q)
  int slot = tid & 7;               // staging 16B slot in 128B row

  const bf16* w1base = W1T + (size_t)j * (HD * XD);
  const bf16* w2g = W2T + (size_t)((j << 4) + l15) * HD;  // row y = l15
  bf16* sH = (bf16*)(smem + 131072);

  f32x4 acc2[2];
#pragma unroll
  for (int f = 0; f < 2; ++f)
#pragma unroll
    for (int r = 0; r < 4; ++r) acc2[f][r] = 0.0f;

  // stage: 8 gload16/thread into buf d: sA rows=x[n0+r], sB rows=W1T[hb*256+r]
  auto stage = [&](int d, int k0, int hb_) {
    char* aD = smem + d * 32768 + (tid << 4);
    char* bD = smem + 65536 + d * 32768 + (tid << 4);
#pragma unroll
    for (int q = 0; q < 4; ++q) {
      int r = (q << 6) + srow;
      int sc = slot ^ (r & 7);
      gload16(XBF + (size_t)(n0 + r) * XD + k0 + (sc << 3), aD + (q << 13));
      gload16(w1base + (size_t)((hb_ << 8) + r) * XD + k0 + (sc << 3), bD + (q << 13));
    }
  };

  // prologue: stage (hb=0, t=0) into buf0
  stage(0, 0, 0);
  asm volatile("s_waitcnt vmcnt(0)" ::: "memory");
  __builtin_amdgcn_s_barrier();

#pragma unroll 1
  for (int hb = 0; hb < 4; ++hb) {
    f32x4 acc1[8][4];
#pragma unroll
    for (int fa = 0; fa < 8; ++fa)
#pragma unroll
      for (int fb = 0; fb < 4; ++fb)
#pragma unroll
        for (int r = 0; r < 4; ++r) acc1[fa][fb][r] = 0.0f;

    int cur = 0;
#pragma unroll 1
    for (int t = 0; t < 8; ++t) {
      // issue next stage BEFORE compute so its latency hides under MFMA
      if (t < 7)            stage(cur ^ 1, (t + 1) << 6, hb);
      else if (hb < 3)      stage(cur ^ 1, 0, hb + 1);
      const char* a_d = smem + cur * 32768;
      const char* b_d = smem + 65536 + cur * 32768;
#pragma unroll
      for (int kk = 0; kk < 2; ++kk) {
        bf16x8 af[8], bg[4];
#pragma unroll
        for (int fa = 0; fa < 8; ++fa) {
          int ra = wn + (fa << 4) + l15;
          int ca = ((kk << 6) + (lg << 4)) ^ ((ra & 7) << 4);
          af[fa] = *(const bf16x8*)(a_d + (ra << 7) + ca);
        }
#pragma unroll
        for (int fb = 0; fb < 4; ++fb) {
          int rb = wh + (fb << 4) + l15;
          int cb = ((kk << 6) + (lg << 4)) ^ ((rb & 7) << 4);
          bg[fb] = *(const bf16x8*)(b_d + (rb << 7) + cb);
        }
        __builtin_amdgcn_s_setprio(1);
#pragma unroll
        for (int fa = 0; fa < 8; ++fa)
#pragma unroll
          for (int fb = 0; fb < 4; ++fb)
            acc1[fa][fb] = __builtin_amdgcn_mfma_f32_16x16x32_bf16(
                af[fa], bg[fb], acc1[fa][fb], 0, 0, 0);
        __builtin_amdgcn_s_setprio(0);
      }
      asm volatile("s_waitcnt vmcnt(0)" ::: "memory");
      __builtin_amdgcn_s_barrier();
      cur ^= 1;
    }

    // ---- b1 + hardtanh -> sH in 4 h-chunks of 64; GEMM2 accumulate per chunk
    float b1v[4];
#pragma unroll
    for (int fb = 0; fb < 4; ++fb)
      b1v[fb] = B1W[(j << 10) + (hb << 8) + wh + (fb << 4) + l15];

#pragma unroll 1
    for (int c = 0; c < 4; ++c) {
      __syncthreads();  // previous chunk's GEMM2 reads done before overwrite
      if ((wid & 3) == c) {
#pragma unroll
        for (int fa = 0; fa < 8; ++fa)
#pragma unroll
          for (int fb = 0; fb < 4; ++fb) {
            int col = (fb << 4) + l15;  // chunk-local h col 0..63
#pragma unroll
            for (int r = 0; r < 4; ++r) {
              int row = wn + (fa << 4) + (lg << 2) + r;
              float v = acc1[fa][fb][r] + b1v[fb];
              v = fminf(1.0f, fmaxf(-1.0f, v));
              int byte = (row << 7) + (((col << 1)) ^ ((row & 7) << 4));
              *(bf16*)((char*)sH + byte) = (bf16)v;
            }
          }
      }
      __syncthreads();  // sH chunk ready
#pragma unroll
      for (int kk2 = 0; kk2 < 2; ++kk2) {
        bf16x8 wg = *(const bf16x8*)(w2g + (hb << 8) + (c << 6) + (kk2 << 5) + (lg << 3));
#pragma unroll
        for (int f = 0; f < 2; ++f) {
          int row = (wid << 5) + (f << 4) + l15;
          int cb = ((kk2 << 6) + (lg << 4)) ^ ((row & 7) << 4);
          bf16x8 hf = *(const bf16x8*)((char*)sH + (row << 7) + cb);
          acc2[f] = __builtin_amdgcn_mfma_f32_16x16x32_bf16(hf, wg, acc2[f], 0, 0, 0);
        }
      }
    }
  }

  // ---- epilogue: b2, stage out tile (reuses sA region), permutation gather
  float b2v = B2W[(j << 4) + l15];
  float* sOut = (float*)smem;              // [256][17] f32 = 17408 B
  int* sIdx = (int*)(smem + 20480);        // [128]
#pragma unroll
  for (int f = 0; f < 2; ++f)
#pragma unroll
    for (int r = 0; r < 4; ++r) {
      int row = (wid << 5) + (f << 4) + (lg << 2) + r;
      sOut[row * 17 + l15] = acc2[f][r] + b2v;
    }
  if (tid < 128) {  // cidx[p][y] = c with permu[p][c][y]==1
    int p = tid >> 4, y = tid & 15;
    int c = 0;
#pragma unroll
    for (int cc = 0; cc < 16; ++cc)
      if (permu[((p << 4) + cc) * 16 + y] > 0.5f) c = cc;
    sIdx[tid] = c;
  }
  __syncthreads();
#pragma unroll 1
  for (int it = 0; it < 16; ++it) {
    int flat = (it << 11) + (tid << 2);   // p[3] n[8] y[4]
    int p = flat >> 12;
    int n = (flat >> 4) & 255;
    int y0 = flat & 15;
    f32x4 v;
#pragma unroll
    for (int q = 0; q < 4; ++q) v[q] = sOut[n * 17 + sIdx[(p << 4) + y0 + q]];
    *(f32x4*)(out + ((size_t)((j << 3) + p) * NN + n0 + n) * YD + y0) = v;
  }
}

extern "C" void kernel_launch(void* const* d_in, const int* in_sizes, int n_in,
                              void* d_out, int out_size, void* d_ws, size_t ws_size,
                              hipStream_t stream) {
  (void)in_sizes; (void)n_in; (void)out_size; (void)ws_size;
  const float* x      = (const float*)d_in[0];
  const float* mu_W1  = (const float*)d_in[1];
  const float* mu_b1  = (const float*)d_in[2];
  const float* mu_W2  = (const float*)d_in[3];
  const float* mu_b2  = (const float*)d_in[4];
  const float* sig_W1 = (const float*)d_in[5];
  const float* sig_b1 = (const float*)d_in[6];
  const float* sig_W2 = (const float*)d_in[7];
  const float* sig_b2 = (const float*)d_in[8];
  const float* e_W1   = (const float*)d_in[9];
  const float* e_b1   = (const float*)d_in[10];
  const float* e_W2   = (const float*)d_in[11];
  const float* e_b2   = (const float*)d_in[12];
  const float* permu  = (const float*)d_in[13];
  float* out = (float*)d_out;

  char* ws = (char*)d_ws;
  bf16* W1T = (bf16*)(ws);
  bf16* W2T = (bf16*)(ws + 67108864);
  bf16* XBF = (bf16*)(ws + 69206016);
  float* B1W = (float*)(ws + 70254592);
  float* B2W = (float*)(ws + 70516736);

  static int lds_set = 0;
  if (!lds_set) {  // idempotent host-side attribute; not a stream op (capture-safe)
    hipFuncSetAttribute((const void*)fused_mlp,
                        hipFuncAttributeMaxDynamicSharedMemorySize, 163840);
    lds_set = 1;
  }

  build_w1t<<<dim3(8192), dim3(256), 0, stream>>>(mu_W1, sig_W1, e_W1, W1T);
  build_small<<<dim3(6404), dim3(256), 0, stream>>>(
      x, mu_W2, sig_W2, e_W2, mu_b1, sig_b1, e_b1, mu_b2, sig_b2, e_b2,
      XBF, W2T, B1W, B2W);
  fused_mlp<<<dim3(256), dim3(512), 163840, stream>>>(
      XBF, W1T, W2T, B1W, B2W, permu, out);
}

// Round 6
// 124.534 us; speedup vs baseline: 2.0761x; 2.0761x over previous
//
#include <hip/hip_runtime.h>
#include <cstdint>
#include <cstddef>

#define J 64
#define XD 512
#define HD 1024
#define YD 16
#define PP 8
#define NN 1024

typedef __bf16 bf16;
typedef __attribute__((ext_vector_type(8))) __bf16 bf16x8;
typedef __attribute__((ext_vector_type(4))) __bf16 bf16x4;
typedef __attribute__((ext_vector_type(4))) float f32x4;

// ---------------- workspace layout (bytes) ----------------
// W1T : J*HD*XD bf16  = 67108864   @ 0
// W2T : J*YD*HD bf16  =  2097152   @ 67108864
// XBF : NN*XD   bf16  =  1048576   @ 69206016
// B1W : J*HD    f32   =   262144   @ 70254592
// B2W : J*YD    f32   =     4096   @ 70516736
// total = 70520832

__device__ __forceinline__ void gload16(const void* g, void* l) {
  __builtin_amdgcn_global_load_lds((__attribute__((address_space(1))) void*)(g),
                                   (__attribute__((address_space(3))) void*)(l),
                                   16, 0, 0);
}

// ---- K1a: W1T[j][h][x] = bf16(mu_W1[x][h] + e_W1[j][x][h]*sig_W1[x][h])
__global__ __launch_bounds__(256) void build_w1t(
    const float* __restrict__ muW1, const float* __restrict__ sigW1,
    const float* __restrict__ eW1, bf16* __restrict__ W1T) {
  __shared__ bf16 sT[64][66];  // [h-local][x-local], pad 66 for bank spread
  int b = blockIdx.x;
  int j = b >> 7;           // 128 tiles per j (8 x-tiles x 16 h-tiles)
  int xt = (b >> 4) & 7;
  int ht = b & 15;
  int x0 = xt << 6, h0 = ht << 6;
  int tid = threadIdx.x;
  int rp = tid >> 4;          // 0..15
  int cp = (tid & 15) << 2;   // 0..60
  const float* eB = eW1 + (size_t)j * (XD * HD);
#pragma unroll
  for (int p = 0; p < 4; ++p) {
    int x = rp + (p << 4);
    size_t gi = (size_t)(x0 + x) * HD + (h0 + cp);
    f32x4 e = *(const f32x4*)(eB + gi);
    f32x4 m = *(const f32x4*)(muW1 + gi);
    f32x4 s = *(const f32x4*)(sigW1 + gi);
#pragma unroll
    for (int i = 0; i < 4; ++i) sT[cp + i][x] = (bf16)(m[i] + e[i] * s[i]);
  }
  __syncthreads();
#pragma unroll
  for (int p = 0; p < 4; ++p) {
    int h = rp + (p << 4);
    bf16x4 v;
#pragma unroll
    for (int i = 0; i < 4; ++i) v[i] = sT[h][cp + i];
    *(bf16x4*)(W1T + (size_t)(j * HD + h0 + h) * XD + (x0 + cp)) = v;
  }
}

// ---- K1b: XBF, W2T, B1W, B2W
__global__ __launch_bounds__(256) void build_small(
    const float* __restrict__ x,
    const float* __restrict__ muW2, const float* __restrict__ sigW2,
    const float* __restrict__ eW2,
    const float* __restrict__ mub1, const float* __restrict__ sigb1,
    const float* __restrict__ eb1,
    const float* __restrict__ mub2, const float* __restrict__ sigb2,
    const float* __restrict__ eb2,
    bf16* __restrict__ XBF, bf16* __restrict__ W2T,
    float* __restrict__ B1W, float* __restrict__ B2W) {
  int i = blockIdx.x * 256 + threadIdx.x;
  const int c0 = NN * XD;        // 524288
  const int c1 = J * YD * HD;    // 1048576
  const int c2 = J * HD;         // 65536
  const int c3 = J * YD;         // 1024
  if (i < c0) { XBF[i] = (bf16)x[i]; return; }
  i -= c0;
  if (i < c1) {
    int h = i & (HD - 1);
    int jy = i >> 10;
    int y = jy & 15;
    int j = jy >> 4;
    float mu = muW2[h * YD + y], sg = sigW2[h * YD + y];
    float e = eW2[((size_t)j * HD + h) * YD + y];
    W2T[i] = (bf16)(mu + e * sg);
    return;
  }
  i -= c1;
  if (i < c2) {
    int h = i & (HD - 1);
    B1W[i] = mub1[h] + eb1[i] * sigb1[h];
    return;
  }
  i -= c2;
  if (i < c3) {
    int y = i & 15;
    B2W[i] = mub2[y] + eb2[i] * sigb2[y];
  }
}

// ---- K2: fused GEMM1 + clip + GEMM2 + permutation scatter
// block = (j, 256-row n tile); 512 threads = 8 waves (4n x 2h), wave tile 64x64
// acc1[4][4]=64 f32 -> total reg demand ~125, fits the 128-VGPR budget (no spill;
// R4/R5's 128x64 wave tile demanded ~180 and spilled 25-34MB/dispatch).
// LDS 160KB: sA dbuf 2x32KB @0, sB dbuf 2x16KB @65536, sH [256][128] 64KB @98304
// counted dbuf: stage(t+1) issued BEFORE compute(t); one vmcnt(0)+s_barrier per tile
__global__ __launch_bounds__(512)
__attribute__((amdgpu_waves_per_eu(2, 2)))
void fused_mlp(
    const bf16* __restrict__ XBF, const bf16* __restrict__ W1T,
    const bf16* __restrict__ W2T, const float* __restrict__ B1W,
    const float* __restrict__ B2W, const float* __restrict__ permu,
    float* __restrict__ out) {
  extern __shared__ char smem[];          // 163840 bytes

  int bid = blockIdx.x;
  // XCD swizzle: XCD x owns j in [8x,8x+8); each j's 4 n-tiles adjacent on one XCD
  int L = ((bid & 7) << 5) | (bid >> 3);
  int j = L >> 2;
  int n0 = (L & 3) << 8;

  int tid = threadIdx.x;
  int wid = tid >> 6;               // 0..7
  int lane = tid & 63;
  int l15 = lane & 15;
  int lg = lane >> 4;               // 0..3
  int wn = (wid >> 1) << 6;         // wave n offset (0,64,128,192)
  int wh = (wid & 1) << 6;          // wave h offset (0,64)
  int srow = tid >> 3;              // staging row 0..63 (+64 per q)
  int slot = tid & 7;               // staging 16B slot in 128B row

  const bf16* w1base = W1T + (size_t)j * (HD * XD);
  const bf16* w2g = W2T + (size_t)((j << 4) + l15) * HD;  // row y = l15
  bf16* sH = (bf16*)(smem + 98304);

  f32x4 acc2[2];
#pragma unroll
  for (int f = 0; f < 2; ++f)
#pragma unroll
    for (int r = 0; r < 4; ++r) acc2[f][r] = 0.0f;

  // stage into buf d: sA = x rows [n0, n0+256), sB = W1T rows [hb*128, +128), k cols [k0,k0+64)
  auto stage = [&](int d, int k0, int hb_) {
    char* aD = smem + d * 32768 + (tid << 4);
    char* bD = smem + 65536 + d * 16384 + (tid << 4);
#pragma unroll
    for (int q = 0; q < 4; ++q) {
      int r = (q << 6) + srow;
      int sc = slot ^ (r & 7);
      gload16(XBF + (size_t)(n0 + r) * XD + k0 + (sc << 3), aD + (q << 13));
      if (q < 2)
        gload16(w1base + (size_t)((hb_ << 7) + r) * XD + k0 + (sc << 3), bD + (q << 13));
    }
  };

  // prologue: stage (hb=0, t=0) into buf0
  stage(0, 0, 0);
  asm volatile("s_waitcnt vmcnt(0)" ::: "memory");
  __builtin_amdgcn_s_barrier();

#pragma unroll 1
  for (int hb = 0; hb < 8; ++hb) {
    f32x4 acc1[4][4];
#pragma unroll
    for (int fa = 0; fa < 4; ++fa)
#pragma unroll
      for (int fb = 0; fb < 4; ++fb)
#pragma unroll
        for (int r = 0; r < 4; ++r) acc1[fa][fb][r] = 0.0f;

    int cur = 0;
#pragma unroll 1
    for (int t = 0; t < 8; ++t) {
      // issue next stage BEFORE compute so its latency hides under MFMA
      if (t < 7)            stage(cur ^ 1, (t + 1) << 6, hb);
      else if (hb < 7)      stage(cur ^ 1, 0, hb + 1);
      const char* a_d = smem + cur * 32768;
      const char* b_d = smem + 65536 + cur * 16384;
#pragma unroll
      for (int kk = 0; kk < 2; ++kk) {
        bf16x8 af[4], bg[4];
#pragma unroll
        for (int fa = 0; fa < 4; ++fa) {
          int ra = wn + (fa << 4) + l15;
          int ca = ((kk << 6) + (lg << 4)) ^ ((ra & 7) << 4);
          af[fa] = *(const bf16x8*)(a_d + (ra << 7) + ca);
        }
#pragma unroll
        for (int fb = 0; fb < 4; ++fb) {
          int rb = wh + (fb << 4) + l15;
          int cb = ((kk << 6) + (lg << 4)) ^ ((rb & 7) << 4);
          bg[fb] = *(const bf16x8*)(b_d + (rb << 7) + cb);
        }
#pragma unroll
        for (int fa = 0; fa < 4; ++fa)
#pragma unroll
          for (int fb = 0; fb < 4; ++fb)
            acc1[fa][fb] = __builtin_amdgcn_mfma_f32_16x16x32_bf16(
                af[fa], bg[fb], acc1[fa][fb], 0, 0, 0);
      }
      asm volatile("s_waitcnt vmcnt(0)" ::: "memory");
      __builtin_amdgcn_s_barrier();
      cur ^= 1;
    }

    // ---- b1 + hardtanh -> sH [256 n][128 h] (swizzled); full panel, no chunking
    float b1v[4];
#pragma unroll
    for (int fb = 0; fb < 4; ++fb)
      b1v[fb] = B1W[(j << 10) + (hb << 7) + wh + (fb << 4) + l15];
#pragma unroll
    for (int fa = 0; fa < 4; ++fa) {
#pragma unroll
      for (int fb = 0; fb < 4; ++fb) {
        int col = wh + (fb << 4) + l15;
#pragma unroll
        for (int r = 0; r < 4; ++r) {
          int row = wn + (fa << 4) + (lg << 2) + r;
          float v = acc1[fa][fb][r] + b1v[fb];
          v = fminf(1.0f, fmaxf(-1.0f, v));
          int byte = (row << 8) + (((col << 1)) ^ ((row & 7) << 4));
          *(bf16*)((char*)sH + byte) = (bf16)v;
        }
      }
    }
    __syncthreads();  // sH panel complete before GEMM2 reads
    // ---- GEMM2: wave owns rows wid*32..+32 of 256; W2 frags from global (L2-hot)
#pragma unroll
    for (int kk2 = 0; kk2 < 4; ++kk2) {
      bf16x8 wg = *(const bf16x8*)(w2g + (hb << 7) + (kk2 << 5) + (lg << 3));
#pragma unroll
      for (int f = 0; f < 2; ++f) {
        int row = (wid << 5) + (f << 4) + l15;
        int cb = ((kk2 << 6) + (lg << 4)) ^ ((row & 7) << 4);
        bf16x8 hf = *(const bf16x8*)((char*)sH + (row << 8) + cb);
        acc2[f] = __builtin_amdgcn_mfma_f32_16x16x32_bf16(hf, wg, acc2[f], 0, 0, 0);
      }
    }
    // no extra barrier: next sH write happens only after next hb's K-loop barriers
  }

  // ---- epilogue: b2, stage out tile (reuses sA region), permutation gather
  float b2v = B2W[(j << 4) + l15];
  float* sOut = (float*)smem;              // [256][17] f32 = 17408 B
  int* sIdx = (int*)(smem + 20480);        // [128]
#pragma unroll
  for (int f = 0; f < 2; ++f)
#pragma unroll
    for (int r = 0; r < 4; ++r) {
      int row = (wid << 5) + (f << 4) + (lg << 2) + r;
      sOut[row * 17 + l15] = acc2[f][r] + b2v;
    }
  if (tid < 128) {  // cidx[p][y] = c with permu[p][c][y]==1
    int p = tid >> 4, y = tid & 15;
    int c = 0;
#pragma unroll
    for (int cc = 0; cc < 16; ++cc)
      if (permu[((p << 4) + cc) * 16 + y] > 0.5f) c = cc;
    sIdx[tid] = c;
  }
  __syncthreads();
#pragma unroll 1
  for (int it = 0; it < 16; ++it) {
    int flat = (it << 11) + (tid << 2);   // p[3] n[8] y[4]
    int p = flat >> 12;
    int n = (flat >> 4) & 255;
    int y0 = flat & 15;
    f32x4 v;
#pragma unroll
    for (int q = 0; q < 4; ++q) v[q] = sOut[n * 17 + sIdx[(p << 4) + y0 + q]];
    *(f32x4*)(out + ((size_t)((j << 3) + p) * NN + n0 + n) * YD + y0) = v;
  }
}

extern "C" void kernel_launch(void* const* d_in, const int* in_sizes, int n_in,
                              void* d_out, int out_size, void* d_ws, size_t ws_size,
                              hipStream_t stream) {
  (void)in_sizes; (void)n_in; (void)out_size; (void)ws_size;
  const float* x      = (const float*)d_in[0];
  const float* mu_W1  = (const float*)d_in[1];
  const float* mu_b1  = (const float*)d_in[2];
  const float* mu_W2  = (const float*)d_in[3];
  const float* mu_b2  = (const float*)d_in[4];
  const float* sig_W1 = (const float*)d_in[5];
  const float* sig_b1 = (const float*)d_in[6];
  const float* sig_W2 = (const float*)d_in[7];
  const float* sig_b2 = (const float*)d_in[8];
  const float* e_W1   = (const float*)d_in[9];
  const float* e_b1   = (const float*)d_in[10];
  const float* e_W2   = (const float*)d_in[11];
  const float* e_b2   = (const float*)d_in[12];
  const float* permu  = (const float*)d_in[13];
  float* out = (float*)d_out;

  char* ws = (char*)d_ws;
  bf16* W1T = (bf16*)(ws);
  bf16* W2T = (bf16*)(ws + 67108864);
  bf16* XBF = (bf16*)(ws + 69206016);
  float* B1W = (float*)(ws + 70254592);
  float* B2W = (float*)(ws + 70516736);

  static int lds_set = 0;
  if (!lds_set) {  // idempotent host-side attribute; not a stream op (capture-safe)
    hipFuncSetAttribute((const void*)fused_mlp,
                        hipFuncAttributeMaxDynamicSharedMemorySize, 163840);
    lds_set = 1;
  }

  build_w1t<<<dim3(8192), dim3(256), 0, stream>>>(mu_W1, sig_W1, e_W1, W1T);
  build_small<<<dim3(6404), dim3(256), 0, stream>>>(
      x, mu_W2, sig_W2, e_W2, mu_b1, sig_b1, e_b1, mu_b2, sig_b2, e_b2,
      XBF, W2T, B1W, B2W);
  fused_mlp<<<dim3(256), dim3(512), 163840, stream>>>(
      XBF, W1T, W2T, B1W, B2W, permu, out);
}